// Round 6
// baseline (433.980 us; speedup 1.0000x reference)
//
#include <hip/hip_runtime.h>
#include <stdint.h>

typedef _Float16 half8 __attribute__((ext_vector_type(8)));
typedef float f32x4 __attribute__((ext_vector_type(4)));

// ---------------- k_pre: M-build (b0-3) + cheb chain (b4) + CSR (b5) + root staging (b6-9) ----------------
__global__ __launch_bounds__(256)
void k_pre(const float* __restrict__ eenc_w, const float* __restrict__ eenc_b,
           const float* __restrict__ nn1_w, const float* __restrict__ nn1_b,
           const float* __restrict__ root_w, const float* __restrict__ x,
           const int* __restrict__ ei, float* __restrict__ Mbuf,
           float* __restrict__ Tx, int* __restrict__ rowptr, int* __restrict__ eord,
           _Float16* __restrict__ Btl) {
  __shared__ __align__(16) float smem[8192];  // 32 KB (cheb/CSR roles)
  int t = threadIdx.x;
  int b = blockIdx.x;
  if (b < 4) {
    // ---- M[l] = [eenc_w @ nn1_w[l] (4 rows); eenc_b @ nn1_w[l] + nn1_b[l] (row 4)] ----
    int l = b;
    if (t < 192) {
      float a0 = 0.f, a1 = 0.f, a2 = 0.f, a3 = 0.f, a4 = 0.f;
      const float* nw = nn1_w + (size_t)l * 36864 + t;
      for (int k = 0; k < 192; ++k) {
        float nv = nw[(size_t)k * 192];
        a0 += eenc_w[k] * nv;
        a1 += eenc_w[192 + k] * nv;
        a2 += eenc_w[384 + k] * nv;
        a3 += eenc_w[576 + k] * nv;
        a4 += eenc_b[k] * nv;
      }
      float* Ml = Mbuf + l * 960;
      Ml[t] = a0; Ml[192 + t] = a1; Ml[384 + t] = a2; Ml[576 + t] = a3;
      Ml[768 + t] = a4 + nn1_b[l * 192 + t];
    }
  } else if (b == 4) {
    // ---- Chebyshev chain: LDS cur[4096], yv[4096]; deg aliases yv; wn/prev in regs ----
    float* cur = smem;
    float* yv = smem + 4096;
    float* deg = yv;
    for (int i = t; i < 1024; i += 256) deg[i] = 0.f;
    __syncthreads();
    for (int e = t; e < 2048; e += 256) atomicAdd(&deg[ei[e]], 1.f);
    __syncthreads();
    float wn[8];
#pragma unroll
    for (int i = 0; i < 8; ++i) {
      int e = t + 256 * i;
      int s = ei[e], d = ei[2048 + e];
      float ds = deg[s], dd = deg[d];
      float a = ds > 0.f ? 1.f / sqrtf(fmaxf(ds, 1.f)) : 0.f;
      float bb = dd > 0.f ? 1.f / sqrtf(fmaxf(dd, 1.f)) : 0.f;
      wn[i] = -a * bb;
    }
    __syncthreads();
    float4 prev[4];
#pragma unroll
    for (int q = 0; q < 4; ++q) {
      int i = t + 256 * q;
      float4 xv = ((const float4*)x)[i];
      ((float4*)cur)[i] = xv;
      ((float4*)Tx)[i] = xv;
    }
    __syncthreads();
    for (int rec = 0; rec < 4; ++rec) {
      for (int i = t; i < 4096; i += 256) yv[i] = 0.f;
      __syncthreads();
#pragma unroll
      for (int i = 0; i < 8; ++i) {
        int e = t + 256 * i;
        int s = ei[e], d = ei[2048 + e];
        float wv = wn[i];
#pragma unroll
        for (int c = 0; c < 4; ++c) atomicAdd(&yv[d * 4 + c], wv * cur[s * 4 + c]);
      }
      __syncthreads();
      float a = rec ? 2.f : 1.f;
#pragma unroll
      for (int q = 0; q < 4; ++q) {
        int i = t + 256 * q;
        float4 y4 = ((float4*)yv)[i];
        float4 c4 = ((float4*)cur)[i];
        float4 n4;
        n4.x = a * y4.x - (rec ? prev[q].x : 0.f);
        n4.y = a * y4.y - (rec ? prev[q].y : 0.f);
        n4.z = a * y4.z - (rec ? prev[q].z : 0.f);
        n4.w = a * y4.w - (rec ? prev[q].w : 0.f);
        prev[q] = c4;
        ((float4*)cur)[i] = n4;
        ((float4*)(Tx + (rec + 1) * 4096))[i] = n4;
      }
      __syncthreads();
    }
  } else if (b == 5) {
    // ---- CSR by dst: rowptr[1025], eord[2048] ----
    int* cnt = (int*)smem;
    int* rp  = (int*)smem + 1024;
    int* wtot = (int*)smem + 2048;
    int lane = t & 63, wv = t >> 6;
    for (int i = t; i < 1024; i += 256) cnt[i] = 0;
    __syncthreads();
    for (int e = t; e < 2048; e += 256) atomicAdd(&cnt[ei[2048 + e]], 1);
    __syncthreads();
    int c0 = cnt[t * 4], c1 = cnt[t * 4 + 1], c2 = cnt[t * 4 + 2], c3 = cnt[t * 4 + 3];
    int s = c0 + c1 + c2 + c3;
    int inc = s;
#pragma unroll
    for (int off = 1; off < 64; off <<= 1) {
      int u = __shfl_up(inc, off);
      if (lane >= off) inc += u;
    }
    if (lane == 63) wtot[wv] = inc;
    __syncthreads();
    int woff = 0;
#pragma unroll
    for (int j = 0; j < 4; ++j) if (j < wv) woff += wtot[j];
    int excl = woff + inc - s;
    int4 r4; r4.x = excl; r4.y = excl + c0; r4.z = excl + c0 + c1; r4.w = excl + c0 + c1 + c2;
    *(int4*)(rowptr + t * 4) = r4;
    if (t == 0) rowptr[1024] = 2048;
    rp[t * 4] = r4.x; rp[t * 4 + 1] = r4.y; rp[t * 4 + 2] = r4.z; rp[t * 4 + 3] = r4.w;
    __syncthreads();
    for (int e = t; e < 2048; e += 256) {
      int d = ei[2048 + e];
      int slot = atomicAdd(&rp[d], 1);
      eord[slot] = e;
    }
  } else {
    // ---- root staging: B rows 960..1151 = f16(root_w[l][m][o]) ----
    int l = b - 6;
    for (int idx = t; idx < 36864; idx += 256) {
      float v = root_w[(size_t)l * 36864 + idx];
      int m = idx / 192, o = idx - m * 192;
      int ck = m >> 3, j = m & 7;
      Btl[(size_t)l * 221184 + ck * 9216 + (size_t)(960 + o) * 8 + j] = (_Float16)v;
    }
  }
}

// ---------------- k_pb: B = f16(M @ W2 + bias) direct; M via scalar (uniform) loads ----------------
// grid (145,4): x<144 -> workers (256 cols, full K=192); x==144,y==0 -> z0 build rider.
__global__ __launch_bounds__(256)
void k_pb(const float* __restrict__ nn2_w, const float* __restrict__ nn2_b,
          const float* __restrict__ Mbuf, _Float16* __restrict__ Btl,
          const float* __restrict__ Tx, const float* __restrict__ cheb_w,
          const float* __restrict__ cheb_b, _Float16* __restrict__ z0) {
  int t = threadIdx.x;
  if (blockIdx.x == 144) {
    if (blockIdx.y != 0) return;
    // ---- z0 = f16(cheb_out) chunk-major, single block rider ----
    for (int i = t; i < 24576; i += 256) {
      int n = i & 1023, ck = i >> 10;
      float tv[5][4];
#pragma unroll
      for (int k = 0; k < 5; ++k) {
        float4 t4 = ((const float4*)(Tx + k * 4096))[n];
        tv[k][0] = t4.x; tv[k][1] = t4.y; tv[k][2] = t4.z; tv[k][3] = t4.w;
      }
      union { _Float16 h[8]; uint4 v; } u;
#pragma unroll
      for (int j = 0; j < 8; ++j) {
        int o = ck * 8 + j;
        float acc = cheb_b[o];
#pragma unroll
        for (int k = 0; k < 5; ++k)
#pragma unroll
          for (int c = 0; c < 4; ++c)
            acc += tv[k][c] * cheb_w[(k * 4 + c) * 192 + o];
        u.h[j] = (_Float16)acc;
      }
      *(uint4*)(z0 + ((size_t)ck * 1024 + n) * 8) = u.v;
    }
    return;
  }
  // ---- worker: pure stream; M from global via uniform (scalar-path) loads ----
  int l = blockIdx.y;
  int col = blockIdx.x * 256 + t;
  const float* Wp = nn2_w + (size_t)l * 7077888 + col;
  const float* Mb = Mbuf + l * 960;
  float a0 = 0.f, a1 = 0.f, a2 = 0.f, a3 = 0.f, a4 = 0.f;
#pragma unroll 16
  for (int k = 0; k < 192; ++k) {
    float wv = Wp[(size_t)k * 36864];
    a0 += Mb[k] * wv;
    a1 += Mb[192 + k] * wv;
    a2 += Mb[384 + k] * wv;
    a3 += Mb[576 + k] * wv;
    a4 += Mb[768 + k] * wv;
  }
  a4 += nn2_b[(size_t)l * 36864 + col];
  int i = col / 192, o = col - i * 192;
  int ck = i >> 3, j = i & 7;
  _Float16* outB = Btl + (size_t)l * 221184 + ck * 9216 + j;
  outB[(size_t)(0 * 192 + o) * 8] = (_Float16)a0;
  outB[(size_t)(1 * 192 + o) * 8] = (_Float16)a1;
  outB[(size_t)(2 * 192 + o) * 8] = (_Float16)a2;
  outB[(size_t)(3 * 192 + o) * 8] = (_Float16)a3;
  outB[(size_t)(4 * 192 + o) * 8] = (_Float16)a4;
}

// ---------------- Y = z16 @ B  (1024 x 1152, K=192), fragments straight from global ----------------
__global__ __launch_bounds__(256)
void k_y(const _Float16* __restrict__ z16, const _Float16* __restrict__ Btl,
         float* __restrict__ Y, int layer) {
  int t = threadIdx.x;
  int w = t >> 6, lane = t & 63, l15 = lane & 15, q4 = lane >> 4;
  int e0 = blockIdx.x * 64, cb = blockIdx.y;
  const _Float16* Bt = Btl + (size_t)layer * 221184;
  const _Float16* ap = z16 + (((size_t)q4 * 1024) + e0 + w * 16 + l15) * 8;
  const _Float16* bp = Bt + (((size_t)q4 * 1152) + cb * 192 + l15) * 8;
  f32x4 acc[12] = {};
#pragma unroll
  for (int ks = 0; ks < 6; ++ks) {
    half8 av = *(const half8*)(ap + (size_t)ks * 4 * 1024 * 8);
#pragma unroll
    for (int nt = 0; nt < 12; ++nt) {
      half8 bv = *(const half8*)(bp + (size_t)ks * 4 * 1152 * 8 + nt * 16 * 8);
      acc[nt] = __builtin_amdgcn_mfma_f32_16x16x32_f16(av, bv, acc[nt], 0, 0, 0);
    }
  }
#pragma unroll
  for (int nt = 0; nt < 12; ++nt) {
    int col = cb * 192 + nt * 16 + l15;
#pragma unroll
    for (int r = 0; r < 4; ++r) {
      int row = e0 + w * 16 + q4 * 4 + r;
      Y[(size_t)row * 1152 + col] = acc[nt][r];
    }
  }
}

// ---------------- gather by dst (CSR) + root + bias + residual + LN + relu (+ final for l==3) ----------------
__global__ __launch_bounds__(256)
void k_gn(const int* __restrict__ ei, const float* __restrict__ eattr,
          const int* __restrict__ rowptr, const int* __restrict__ eord,
          const float* __restrict__ Y, const float* __restrict__ hp,
          const float* __restrict__ cbv, const float* __restrict__ gg,
          const float* __restrict__ bb, float* __restrict__ ho,
          _Float16* __restrict__ zo, const float* __restrict__ out_w,
          const float* __restrict__ out_b, float* __restrict__ outp, int l) {
  int t = threadIdx.x, w = t >> 6, lane = t & 63;
  int n = blockIdx.x * 4 + w;
  int o0 = lane, o1 = lane + 64, o2 = lane + 128;
  float v0 = 0.f, v1 = 0.f, v2 = 0.f;
  int beg = rowptr[n], end = rowptr[n + 1];
  for (int idx = beg; idx < end; ++idx) {
    int e = eord[idx];
    int s = ei[e];
    float4 u = ((const float4*)eattr)[e];
    const float* yr = Y + (size_t)s * 1152;
    v0 += yr[o0] * u.x + yr[192 + o0] * u.y + yr[384 + o0] * u.z + yr[576 + o0] * u.w + yr[768 + o0];
    v1 += yr[o1] * u.x + yr[192 + o1] * u.y + yr[384 + o1] * u.z + yr[576 + o1] * u.w + yr[768 + o1];
    v2 += yr[o2] * u.x + yr[192 + o2] * u.y + yr[384 + o2] * u.z + yr[576 + o2] * u.w + yr[768 + o2];
  }
  const float* yn = Y + (size_t)n * 1152 + 960;
  v0 += yn[o0] + cbv[o0]; v1 += yn[o1] + cbv[o1]; v2 += yn[o2] + cbv[o2];
  if (l > 0) {
    v0 += hp[n * 192 + o0]; v1 += hp[n * 192 + o1]; v2 += hp[n * 192 + o2];
  }
  if (l < 3) {
    ho[n * 192 + o0] = v0; ho[n * 192 + o1] = v1; ho[n * 192 + o2] = v2;
  }
  float s1 = v0 + v1 + v2, s2 = v0 * v0 + v1 * v1 + v2 * v2;
#pragma unroll
  for (int off = 32; off >= 1; off >>= 1) {
    s1 += __shfl_xor(s1, off);
    s2 += __shfl_xor(s2, off);
  }
  float mu = s1 * (1.f / 192.f);
  float var = s2 * (1.f / 192.f) - mu * mu;
  float rcp = rsqrtf(var + 1e-5f);
  float z0v = fmaxf((v0 - mu) * rcp * gg[o0] + bb[o0], 0.f);
  float z1v = fmaxf((v1 - mu) * rcp * gg[o1] + bb[o1], 0.f);
  float z2v = fmaxf((v2 - mu) * rcp * gg[o2] + bb[o2], 0.f);
  if (l < 3) {
    zo[((size_t)(o0 >> 3) * 1024 + n) * 8 + (o0 & 7)] = (_Float16)z0v;
    zo[((size_t)(o1 >> 3) * 1024 + n) * 8 + (o1 & 7)] = (_Float16)z1v;
    zo[((size_t)(o2 >> 3) * 1024 + n) * 8 + (o2 & 7)] = (_Float16)z2v;
  } else {
    float a0 = z0v * out_w[o0 * 2] + z1v * out_w[o1 * 2] + z2v * out_w[o2 * 2];
    float a1 = z0v * out_w[o0 * 2 + 1] + z1v * out_w[o1 * 2 + 1] + z2v * out_w[o2 * 2 + 1];
#pragma unroll
    for (int off = 32; off >= 1; off >>= 1) {
      a0 += __shfl_xor(a0, off);
      a1 += __shfl_xor(a1, off);
    }
    if (lane == 0) {
      outp[n * 2] = a0 + out_b[0];
      outp[n * 2 + 1] = a1 + out_b[1];
    }
  }
}

// ---------------- launch ----------------
extern "C" void kernel_launch(void* const* d_in, const int* in_sizes, int n_in,
                              void* d_out, int out_size, void* d_ws, size_t ws_size,
                              hipStream_t stream) {
  const float* x      = (const float*)d_in[0];
  const int*   ei     = (const int*)  d_in[1];
  const float* eattr  = (const float*)d_in[2];
  const float* cheb_w = (const float*)d_in[4];
  const float* cheb_b = (const float*)d_in[5];
  const float* eenc_w = (const float*)d_in[6];
  const float* eenc_b = (const float*)d_in[7];
  const float* nn1_w  = (const float*)d_in[8];
  const float* nn1_b  = (const float*)d_in[9];
  const float* nn2_w  = (const float*)d_in[10];
  const float* nn2_b  = (const float*)d_in[11];
  const float* root_w = (const float*)d_in[12];
  const float* conv_b = (const float*)d_in[13];
  const float* ln_g   = (const float*)d_in[14];
  const float* ln_bb  = (const float*)d_in[15];
  const float* out_w  = (const float*)d_in[16];
  const float* out_b  = (const float*)d_in[17];
  float* outp = (float*)d_out;
  (void)in_sizes; (void)n_in; (void)out_size; (void)ws_size;

  char* p = (char*)d_ws;
  _Float16* Btl = (_Float16*)p; p += (size_t)4 * 221184 * 2;   // 1.77 MB
  float* Tx     = (float*)p;    p += 5 * 4096 * 4;
  float* Y      = (float*)p;    p += (size_t)1024 * 1152 * 4;  // 4.7 MB
  float* hA     = (float*)p;    p += 196608 * 4;
  float* hB     = (float*)p;    p += 196608 * 4;
  _Float16* z0  = (_Float16*)p; p += 196608 * 2;
  _Float16* zA  = (_Float16*)p; p += 196608 * 2;
  _Float16* zB  = (_Float16*)p; p += 196608 * 2;
  float* Mbuf   = (float*)p;    p += 4 * 960 * 4;
  int* rowptr   = (int*)p;      p += 1056 * 4;
  int* eord     = (int*)p;      p += 2048 * 4;

  k_pre<<<10, 256, 0, stream>>>(eenc_w, eenc_b, nn1_w, nn1_b, root_w, x, ei,
                                Mbuf, Tx, rowptr, eord, Btl);
  k_pb<<<dim3(145, 4), 256, 0, stream>>>(nn2_w, nn2_b, Mbuf, Btl, Tx,
                                         cheb_w, cheb_b, z0);

  const _Float16* zin[4] = {z0, zA, zB, zA};
  _Float16* zout[4] = {zA, zB, zA, zA};       // zout[3] unused
  float* hout[4] = {hA, hB, hA, hA};          // hout[3] unused
  const float* hres[4] = {hA, hA, hB, hA};    // hres[0] unused
  for (int l = 0; l < 4; ++l) {
    k_y<<<dim3(16, 6), 256, 0, stream>>>(zin[l], Btl, Y, l);
    k_gn<<<256, 256, 0, stream>>>(ei, eattr, rowptr, eord, Y, hres[l],
                                  conv_b + (size_t)l * 192,
                                  ln_g + (size_t)((l == 3) ? 0 : (l + 1)) * 192,
                                  ln_bb + (size_t)((l == 3) ? 0 : (l + 1)) * 192,
                                  hout[l], zout[l], out_w, out_b, outp, l);
  }
}

// Round 7
// 321.444 us; speedup vs baseline: 1.3501x; 1.3501x over previous
//
#include <hip/hip_runtime.h>
#include <stdint.h>

typedef _Float16 half8 __attribute__((ext_vector_type(8)));
typedef float f32x4 __attribute__((ext_vector_type(4)));

typedef const __attribute__((address_space(1))) void* gptr_t;
typedef __attribute__((address_space(3))) void* lptr_t;
static __device__ __forceinline__ void gll16(const void* g, void* l) {
  __builtin_amdgcn_global_load_lds((gptr_t)(unsigned long long)g,
                                   (lptr_t)(unsigned int)(unsigned long long)l,
                                   16, 0, 0);
}

// ---------------- k_pre: M-build (b0-3) + cheb chain (b4) + CSR (b5) ----------------
__global__ __launch_bounds__(256)
void k_pre(const float* __restrict__ eenc_w, const float* __restrict__ eenc_b,
           const float* __restrict__ nn1_w, const float* __restrict__ nn1_b,
           const float* __restrict__ x, const int* __restrict__ ei,
           float* __restrict__ Mbuf, float* __restrict__ Tx,
           int* __restrict__ rowptr, int* __restrict__ eord) {
  __shared__ __align__(16) float smem[8192];  // 32 KB (cheb/CSR roles)
  int t = threadIdx.x;
  int b = blockIdx.x;
  if (b < 4) {
    // ---- M[l] = [eenc_w @ nn1_w[l] (4 rows); eenc_b @ nn1_w[l] + nn1_b[l] (row 4)] ----
    int l = b;
    if (t < 192) {
      float a0 = 0.f, a1 = 0.f, a2 = 0.f, a3 = 0.f, a4 = 0.f;
      const float* nw = nn1_w + (size_t)l * 36864 + t;
      for (int k = 0; k < 192; ++k) {
        float nv = nw[(size_t)k * 192];
        a0 += eenc_w[k] * nv;
        a1 += eenc_w[192 + k] * nv;
        a2 += eenc_w[384 + k] * nv;
        a3 += eenc_w[576 + k] * nv;
        a4 += eenc_b[k] * nv;
      }
      float* Ml = Mbuf + l * 960;
      Ml[t] = a0; Ml[192 + t] = a1; Ml[384 + t] = a2; Ml[576 + t] = a3;
      Ml[768 + t] = a4 + nn1_b[l * 192 + t];
    }
  } else if (b == 4) {
    // ---- Chebyshev chain: LDS cur[4096], yv[4096]; deg aliases yv; wn/prev in regs ----
    float* cur = smem;
    float* yv = smem + 4096;
    float* deg = yv;
    for (int i = t; i < 1024; i += 256) deg[i] = 0.f;
    __syncthreads();
    for (int e = t; e < 2048; e += 256) atomicAdd(&deg[ei[e]], 1.f);
    __syncthreads();
    float wn[8];
#pragma unroll
    for (int i = 0; i < 8; ++i) {
      int e = t + 256 * i;
      int s = ei[e], d = ei[2048 + e];
      float ds = deg[s], dd = deg[d];
      float a = ds > 0.f ? 1.f / sqrtf(fmaxf(ds, 1.f)) : 0.f;
      float bb = dd > 0.f ? 1.f / sqrtf(fmaxf(dd, 1.f)) : 0.f;
      wn[i] = -a * bb;
    }
    __syncthreads();
    float4 prev[4];
#pragma unroll
    for (int q = 0; q < 4; ++q) {
      int i = t + 256 * q;
      float4 xv = ((const float4*)x)[i];
      ((float4*)cur)[i] = xv;
      ((float4*)Tx)[i] = xv;
    }
    __syncthreads();
    for (int rec = 0; rec < 4; ++rec) {
      for (int i = t; i < 4096; i += 256) yv[i] = 0.f;
      __syncthreads();
#pragma unroll
      for (int i = 0; i < 8; ++i) {
        int e = t + 256 * i;
        int s = ei[e], d = ei[2048 + e];
        float wv = wn[i];
#pragma unroll
        for (int c = 0; c < 4; ++c) atomicAdd(&yv[d * 4 + c], wv * cur[s * 4 + c]);
      }
      __syncthreads();
      float a = rec ? 2.f : 1.f;
#pragma unroll
      for (int q = 0; q < 4; ++q) {
        int i = t + 256 * q;
        float4 y4 = ((float4*)yv)[i];
        float4 c4 = ((float4*)cur)[i];
        float4 n4;
        n4.x = a * y4.x - (rec ? prev[q].x : 0.f);
        n4.y = a * y4.y - (rec ? prev[q].y : 0.f);
        n4.z = a * y4.z - (rec ? prev[q].z : 0.f);
        n4.w = a * y4.w - (rec ? prev[q].w : 0.f);
        prev[q] = c4;
        ((float4*)cur)[i] = n4;
        ((float4*)(Tx + (rec + 1) * 4096))[i] = n4;
      }
      __syncthreads();
    }
  } else {
    // ---- CSR by dst: rowptr[1025], eord[2048] ----
    int* cnt = (int*)smem;
    int* rp  = (int*)smem + 1024;
    int* wtot = (int*)smem + 2048;
    int lane = t & 63, wv = t >> 6;
    for (int i = t; i < 1024; i += 256) cnt[i] = 0;
    __syncthreads();
    for (int e = t; e < 2048; e += 256) atomicAdd(&cnt[ei[2048 + e]], 1);
    __syncthreads();
    int c0 = cnt[t * 4], c1 = cnt[t * 4 + 1], c2 = cnt[t * 4 + 2], c3 = cnt[t * 4 + 3];
    int s = c0 + c1 + c2 + c3;
    int inc = s;
#pragma unroll
    for (int off = 1; off < 64; off <<= 1) {
      int u = __shfl_up(inc, off);
      if (lane >= off) inc += u;
    }
    if (lane == 63) wtot[wv] = inc;
    __syncthreads();
    int woff = 0;
#pragma unroll
    for (int j = 0; j < 4; ++j) if (j < wv) woff += wtot[j];
    int excl = woff + inc - s;
    int4 r4; r4.x = excl; r4.y = excl + c0; r4.z = excl + c0 + c1; r4.w = excl + c0 + c1 + c2;
    *(int4*)(rowptr + t * 4) = r4;
    if (t == 0) rowptr[1024] = 2048;
    rp[t * 4] = r4.x; rp[t * 4 + 1] = r4.y; rp[t * 4 + 2] = r4.z; rp[t * 4 + 3] = r4.w;
    __syncthreads();
    for (int e = t; e < 2048; e += 256) {
      int d = ei[2048 + e];
      int slot = atomicAdd(&rp[d], 1);
      eord[slot] = e;
    }
  }
}

// ---------------- k_pb: Ppart = M @ W2 k-split, W2 staged via global_load_lds dbuf ----------------
// grid (72,4,2): col-tile 512 x layer x k-half(96). LDS: 2x16KB tile + 960 M = 36.6KB.
__global__ __launch_bounds__(256)
void k_pb(const float* __restrict__ nn2_w, const float* __restrict__ Mbuf,
          float* __restrict__ Ppart) {
  __shared__ __align__(16) float smem[9152];  // buf0 [0,4096), buf1 [4096,8192), M [8192,9152)
  int t = threadIdx.x;
  int w = t >> 6, lane = t & 63;
  int l = blockIdx.y, kc = blockIdx.z;
  int col0 = blockIdx.x * 512;
  for (int i = t; i < 960; i += 256) smem[8192 + i] = Mbuf[l * 960 + i];
  const float* W2l = nn2_w + (size_t)l * 7077888;
  int k0 = kc * 96;

  // stage tile (8 k-rows x 512 cols, 16KB) into buf b; 16 chunks of 1KB, wave w takes j*4+w
#define STAGE(b, tile)                                                          \
  {                                                                             \
    const float* rowbase = W2l + (size_t)(k0 + (tile) * 8) * 36864 + col0;      \
    char* lb = (char*)(smem + (b) * 4096);                                      \
    _Pragma("unroll")                                                           \
    for (int j = 0; j < 4; ++j) {                                               \
      int idx = j * 4 + w;                                                      \
      int row = idx >> 1, sub = idx & 1;                                        \
      gll16((const char*)(rowbase + (size_t)row * 36864 + sub * 256) + lane * 16, \
            lb + row * 2048 + sub * 1024 + lane * 16);                          \
    }                                                                           \
  }

  float a[5][2] = {};
  STAGE(0, 0);
  __syncthreads();
  int buf = 0;
  for (int tile = 0; tile < 12; ++tile) {
    if (tile < 11) STAGE(buf ^ 1, tile + 1);
    const float* wb = smem + buf * 4096;
    const float* Ml = smem + 8192;
    int kb = k0 + tile * 8;
#pragma unroll
    for (int r = 0; r < 8; ++r) {
      float w0 = wb[r * 512 + 2 * t];
      float w1 = wb[r * 512 + 2 * t + 1];
      int k = kb + r;
#pragma unroll
      for (int c = 0; c < 5; ++c) {
        float m = Ml[c * 192 + k];
        a[c][0] += m * w0;
        a[c][1] += m * w1;
      }
    }
    __syncthreads();
    buf ^= 1;
  }
#undef STAGE
  float* Pp = Ppart + ((size_t)(kc * 4 + l) * 5) * 36864 + col0 + 2 * t;
#pragma unroll
  for (int c = 0; c < 5; ++c) {
    Pp[(size_t)c * 36864] = a[c][0];
    Pp[(size_t)c * 36864 + 1] = a[c][1];
  }
}

// ---------------- stage B f16 chunk-major (y<4) + cheb_out -> z0 f16 chunk-major (y==4) ----------------
__global__ __launch_bounds__(256)
void k_stage(const float* __restrict__ Ppart, const float* __restrict__ nn2_b,
             const float* __restrict__ root_w, _Float16* __restrict__ Btl,
             const float* __restrict__ Tx, const float* __restrict__ cheb_w,
             const float* __restrict__ cheb_b, _Float16* __restrict__ z0) {
  int t = threadIdx.x;
  if (blockIdx.y < 4) {
    int ck = blockIdx.x, l = blockIdx.y;
    _Float16* out = Btl + (size_t)l * 221184 + ck * 9216;
#pragma unroll
    for (int it = 0; it < 5; ++it) {
      int n = it * 256 + t;
      if (n >= 1152) break;
      union { _Float16 h[8]; uint4 v; } u;
      if (n < 960) {
        int c = n / 192, o = n - c * 192;
        const float* P0 = Ppart + ((size_t)(0 * 4 + l) * 5 + c) * 36864;
        const float* P1 = Ppart + ((size_t)(1 * 4 + l) * 5 + c) * 36864;
#pragma unroll
        for (int j = 0; j < 8; ++j) {
          int io = (ck * 8 + j) * 192 + o;
          float val = P0[io] + P1[io];
          if (c == 4) val += nn2_b[(size_t)l * 36864 + io];
          u.h[j] = (_Float16)val;
        }
      } else {
        int o = n - 960;
#pragma unroll
        for (int j = 0; j < 8; ++j)
          u.h[j] = (_Float16)root_w[(size_t)l * 36864 + (ck * 8 + j) * 192 + o];
      }
      *(uint4*)(out + (size_t)n * 8) = u.v;
    }
  } else {
    // cheb_out: z0[(ck*1024+n)*8+j] = f16( cheb_b[o] + sum Tx[k][n][c]*cheb_w[k*4+c][o] ), o=ck*8+j
    for (int i = blockIdx.x * 256 + t; i < 24576; i += 6144) {
      int n = i & 1023, ck = i >> 10;
      float tv[5][4];
#pragma unroll
      for (int k = 0; k < 5; ++k) {
        float4 t4 = ((const float4*)(Tx + k * 4096))[n];
        tv[k][0] = t4.x; tv[k][1] = t4.y; tv[k][2] = t4.z; tv[k][3] = t4.w;
      }
      union { _Float16 h[8]; uint4 v; } u;
#pragma unroll
      for (int j = 0; j < 8; ++j) {
        int o = ck * 8 + j;
        float acc = cheb_b[o];
#pragma unroll
        for (int k = 0; k < 5; ++k)
#pragma unroll
          for (int c = 0; c < 4; ++c)
            acc += tv[k][c] * cheb_w[(k * 4 + c) * 192 + o];
        u.h[j] = (_Float16)acc;
      }
      *(uint4*)(z0 + ((size_t)ck * 1024 + n) * 8) = u.v;
    }
  }
}

// ---------------- Y = z16 @ B  (1024 x 1152, K=192), fragments straight from global ----------------
__global__ __launch_bounds__(256)
void k_y(const _Float16* __restrict__ z16, const _Float16* __restrict__ Btl,
         float* __restrict__ Y, int layer) {
  int t = threadIdx.x;
  int w = t >> 6, lane = t & 63, l15 = lane & 15, q4 = lane >> 4;
  int e0 = blockIdx.x * 64, cb = blockIdx.y;
  const _Float16* Bt = Btl + (size_t)layer * 221184;
  const _Float16* ap = z16 + (((size_t)q4 * 1024) + e0 + w * 16 + l15) * 8;
  const _Float16* bp = Bt + (((size_t)q4 * 1152) + cb * 192 + l15) * 8;
  f32x4 acc[12] = {};
#pragma unroll
  for (int ks = 0; ks < 6; ++ks) {
    half8 av = *(const half8*)(ap + (size_t)ks * 4 * 1024 * 8);
#pragma unroll
    for (int nt = 0; nt < 12; ++nt) {
      half8 bv = *(const half8*)(bp + (size_t)ks * 4 * 1152 * 8 + nt * 16 * 8);
      acc[nt] = __builtin_amdgcn_mfma_f32_16x16x32_f16(av, bv, acc[nt], 0, 0, 0);
    }
  }
#pragma unroll
  for (int nt = 0; nt < 12; ++nt) {
    int col = cb * 192 + nt * 16 + l15;
#pragma unroll
    for (int r = 0; r < 4; ++r) {
      int row = e0 + w * 16 + q4 * 4 + r;
      Y[(size_t)row * 1152 + col] = acc[nt][r];
    }
  }
}

// ---------------- gather by dst (CSR) + root + bias + residual + LN + relu (+ final for l==3) ----------------
__global__ __launch_bounds__(256)
void k_gn(const int* __restrict__ ei, const float* __restrict__ eattr,
          const int* __restrict__ rowptr, const int* __restrict__ eord,
          const float* __restrict__ Y, const float* __restrict__ hp,
          const float* __restrict__ cbv, const float* __restrict__ gg,
          const float* __restrict__ bb, float* __restrict__ ho,
          _Float16* __restrict__ zo, const float* __restrict__ out_w,
          const float* __restrict__ out_b, float* __restrict__ outp, int l) {
  int t = threadIdx.x, w = t >> 6, lane = t & 63;
  int n = blockIdx.x * 4 + w;
  int o0 = lane, o1 = lane + 64, o2 = lane + 128;
  float v0 = 0.f, v1 = 0.f, v2 = 0.f;
  int beg = rowptr[n], end = rowptr[n + 1];
  for (int idx = beg; idx < end; ++idx) {
    int e = eord[idx];
    int s = ei[e];
    float4 u = ((const float4*)eattr)[e];
    const float* yr = Y + (size_t)s * 1152;
    v0 += yr[o0] * u.x + yr[192 + o0] * u.y + yr[384 + o0] * u.z + yr[576 + o0] * u.w + yr[768 + o0];
    v1 += yr[o1] * u.x + yr[192 + o1] * u.y + yr[384 + o1] * u.z + yr[576 + o1] * u.w + yr[768 + o1];
    v2 += yr[o2] * u.x + yr[192 + o2] * u.y + yr[384 + o2] * u.z + yr[576 + o2] * u.w + yr[768 + o2];
  }
  const float* yn = Y + (size_t)n * 1152 + 960;
  v0 += yn[o0] + cbv[o0]; v1 += yn[o1] + cbv[o1]; v2 += yn[o2] + cbv[o2];
  if (l > 0) {
    v0 += hp[n * 192 + o0]; v1 += hp[n * 192 + o1]; v2 += hp[n * 192 + o2];
  }
  if (l < 3) {
    ho[n * 192 + o0] = v0; ho[n * 192 + o1] = v1; ho[n * 192 + o2] = v2;
  }
  float s1 = v0 + v1 + v2, s2 = v0 * v0 + v1 * v1 + v2 * v2;
#pragma unroll
  for (int off = 32; off >= 1; off >>= 1) {
    s1 += __shfl_xor(s1, off);
    s2 += __shfl_xor(s2, off);
  }
  float mu = s1 * (1.f / 192.f);
  float var = s2 * (1.f / 192.f) - mu * mu;
  float rcp = rsqrtf(var + 1e-5f);
  float z0v = fmaxf((v0 - mu) * rcp * gg[o0] + bb[o0], 0.f);
  float z1v = fmaxf((v1 - mu) * rcp * gg[o1] + bb[o1], 0.f);
  float z2v = fmaxf((v2 - mu) * rcp * gg[o2] + bb[o2], 0.f);
  if (l < 3) {
    zo[((size_t)(o0 >> 3) * 1024 + n) * 8 + (o0 & 7)] = (_Float16)z0v;
    zo[((size_t)(o1 >> 3) * 1024 + n) * 8 + (o1 & 7)] = (_Float16)z1v;
    zo[((size_t)(o2 >> 3) * 1024 + n) * 8 + (o2 & 7)] = (_Float16)z2v;
  } else {
    float a0 = z0v * out_w[o0 * 2] + z1v * out_w[o1 * 2] + z2v * out_w[o2 * 2];
    float a1 = z0v * out_w[o0 * 2 + 1] + z1v * out_w[o1 * 2 + 1] + z2v * out_w[o2 * 2 + 1];
#pragma unroll
    for (int off = 32; off >= 1; off >>= 1) {
      a0 += __shfl_xor(a0, off);
      a1 += __shfl_xor(a1, off);
    }
    if (lane == 0) {
      outp[n * 2] = a0 + out_b[0];
      outp[n * 2 + 1] = a1 + out_b[1];
    }
  }
}

// ---------------- launch ----------------
extern "C" void kernel_launch(void* const* d_in, const int* in_sizes, int n_in,
                              void* d_out, int out_size, void* d_ws, size_t ws_size,
                              hipStream_t stream) {
  const float* x      = (const float*)d_in[0];
  const int*   ei     = (const int*)  d_in[1];
  const float* eattr  = (const float*)d_in[2];
  const float* cheb_w = (const float*)d_in[4];
  const float* cheb_b = (const float*)d_in[5];
  const float* eenc_w = (const float*)d_in[6];
  const float* eenc_b = (const float*)d_in[7];
  const float* nn1_w  = (const float*)d_in[8];
  const float* nn1_b  = (const float*)d_in[9];
  const float* nn2_w  = (const float*)d_in[10];
  const float* nn2_b  = (const float*)d_in[11];
  const float* root_w = (const float*)d_in[12];
  const float* conv_b = (const float*)d_in[13];
  const float* ln_g   = (const float*)d_in[14];
  const float* ln_bb  = (const float*)d_in[15];
  const float* out_w  = (const float*)d_in[16];
  const float* out_b  = (const float*)d_in[17];
  float* outp = (float*)d_out;
  (void)in_sizes; (void)n_in; (void)out_size; (void)ws_size;

  char* p = (char*)d_ws;
  _Float16* Btl = (_Float16*)p; p += (size_t)4 * 221184 * 2;        // 1.77 MB
  float* Ppart  = (float*)p;    p += (size_t)2 * 4 * 5 * 36864 * 4; // 5.9 MB
  float* Tx     = (float*)p;    p += 5 * 4096 * 4;
  float* Y      = (float*)p;    p += (size_t)1024 * 1152 * 4;       // 4.7 MB
  float* hA     = (float*)p;    p += 196608 * 4;
  float* hB     = (float*)p;    p += 196608 * 4;
  _Float16* z0  = (_Float16*)p; p += 196608 * 2;
  _Float16* zA  = (_Float16*)p; p += 196608 * 2;
  _Float16* zB  = (_Float16*)p; p += 196608 * 2;
  float* Mbuf   = (float*)p;    p += 4 * 960 * 4;
  int* rowptr   = (int*)p;      p += 1056 * 4;
  int* eord     = (int*)p;      p += 2048 * 4;

  k_pre<<<6, 256, 0, stream>>>(eenc_w, eenc_b, nn1_w, nn1_b, x, ei,
                               Mbuf, Tx, rowptr, eord);
  k_pb<<<dim3(72, 4, 2), 256, 0, stream>>>(nn2_w, Mbuf, Ppart);
  k_stage<<<dim3(24, 5), 256, 0, stream>>>(Ppart, nn2_b, root_w, Btl, Tx,
                                           cheb_w, cheb_b, z0);

  const _Float16* zin[4] = {z0, zA, zB, zA};
  _Float16* zout[4] = {zA, zB, zA, zA};       // zout[3] unused
  float* hout[4] = {hA, hB, hA, hA};          // hout[3] unused
  const float* hres[4] = {hA, hA, hB, hA};    // hres[0] unused
  for (int l = 0; l < 4; ++l) {
    k_y<<<dim3(16, 6), 256, 0, stream>>>(zin[l], Btl, Y, l);
    k_gn<<<256, 256, 0, stream>>>(ei, eattr, rowptr, eord, Y, hres[l],
                                  conv_b + (size_t)l * 192,
                                  ln_g + (size_t)((l == 3) ? 0 : (l + 1)) * 192,
                                  ln_bb + (size_t)((l == 3) ? 0 : (l + 1)) * 192,
                                  hout[l], zout[l], out_w, out_b, outp, l);
  }
}

// Round 8
// 287.039 us; speedup vs baseline: 1.5119x; 1.1199x over previous
//
#include <hip/hip_runtime.h>
#include <stdint.h>

typedef _Float16 half8 __attribute__((ext_vector_type(8)));
typedef float f32x4 __attribute__((ext_vector_type(4)));

typedef const __attribute__((address_space(1))) void* gptr_t;
typedef __attribute__((address_space(3))) void* lptr_t;
static __device__ __forceinline__ void gll16(const void* g, void* l) {
  __builtin_amdgcn_global_load_lds((gptr_t)(unsigned long long)g,
                                   (lptr_t)(unsigned int)(unsigned long long)l,
                                   16, 0, 0);
}

// ---- k_pb: Btl = f16(M @ W2 + nn2_b) streamed via wave-private counted-vmcnt gll16 pipeline.
// Riders: (72,0) cheb chain, (72,1) CSR, (73,y) root staging. Workers: bx<72, 512 cols x layer by.
__global__ __launch_bounds__(256)
void k_pb(const float* __restrict__ nn2_w, const float* __restrict__ nn2_b,
          const float* __restrict__ eenc_w, const float* __restrict__ eenc_b,
          const float* __restrict__ nn1_w, const float* __restrict__ nn1_b,
          const float* __restrict__ root_w, _Float16* __restrict__ Btl,
          const float* __restrict__ x, const int* __restrict__ ei,
          float* __restrict__ Tx, int* __restrict__ rowptr, int* __restrict__ eord) {
  __shared__ __align__(16) float smem[17344];  // waves: 4x4x4KB tiles [0,16384); M [16384,17344)
  int t = threadIdx.x;
  if (blockIdx.x >= 72) {
    if (blockIdx.x == 72) {
      if (blockIdx.y == 0) {
        // ---- Chebyshev chain (r5/r7-verified) ----
        float* cur = smem;
        float* yv = smem + 4096;
        float* deg = yv;
        for (int i = t; i < 1024; i += 256) deg[i] = 0.f;
        __syncthreads();
        for (int e = t; e < 2048; e += 256) atomicAdd(&deg[ei[e]], 1.f);
        __syncthreads();
        float wn[8];
#pragma unroll
        for (int i = 0; i < 8; ++i) {
          int e = t + 256 * i;
          int s = ei[e], d = ei[2048 + e];
          float ds = deg[s], dd = deg[d];
          float a = ds > 0.f ? 1.f / sqrtf(fmaxf(ds, 1.f)) : 0.f;
          float bb = dd > 0.f ? 1.f / sqrtf(fmaxf(dd, 1.f)) : 0.f;
          wn[i] = -a * bb;
        }
        __syncthreads();
        float4 prev[4];
#pragma unroll
        for (int q = 0; q < 4; ++q) {
          int i = t + 256 * q;
          float4 xv = ((const float4*)x)[i];
          ((float4*)cur)[i] = xv;
          ((float4*)Tx)[i] = xv;
        }
        __syncthreads();
        for (int rec = 0; rec < 4; ++rec) {
          for (int i = t; i < 4096; i += 256) yv[i] = 0.f;
          __syncthreads();
#pragma unroll
          for (int i = 0; i < 8; ++i) {
            int e = t + 256 * i;
            int s = ei[e], d = ei[2048 + e];
            float wv = wn[i];
#pragma unroll
            for (int c = 0; c < 4; ++c) atomicAdd(&yv[d * 4 + c], wv * cur[s * 4 + c]);
          }
          __syncthreads();
          float a = rec ? 2.f : 1.f;
#pragma unroll
          for (int q = 0; q < 4; ++q) {
            int i = t + 256 * q;
            float4 y4 = ((float4*)yv)[i];
            float4 c4 = ((float4*)cur)[i];
            float4 n4;
            n4.x = a * y4.x - (rec ? prev[q].x : 0.f);
            n4.y = a * y4.y - (rec ? prev[q].y : 0.f);
            n4.z = a * y4.z - (rec ? prev[q].z : 0.f);
            n4.w = a * y4.w - (rec ? prev[q].w : 0.f);
            prev[q] = c4;
            ((float4*)cur)[i] = n4;
            ((float4*)(Tx + (rec + 1) * 4096))[i] = n4;
          }
          __syncthreads();
        }
      } else if (blockIdx.y == 1) {
        // ---- CSR by dst (r5/r7-verified) ----
        int* cnt = (int*)smem;
        int* rp  = (int*)smem + 1024;
        int* wtot = (int*)smem + 2048;
        int lane = t & 63, wv = t >> 6;
        for (int i = t; i < 1024; i += 256) cnt[i] = 0;
        __syncthreads();
        for (int e = t; e < 2048; e += 256) atomicAdd(&cnt[ei[2048 + e]], 1);
        __syncthreads();
        int c0 = cnt[t * 4], c1 = cnt[t * 4 + 1], c2 = cnt[t * 4 + 2], c3 = cnt[t * 4 + 3];
        int s = c0 + c1 + c2 + c3;
        int inc = s;
#pragma unroll
        for (int off = 1; off < 64; off <<= 1) {
          int u = __shfl_up(inc, off);
          if (lane >= off) inc += u;
        }
        if (lane == 63) wtot[wv] = inc;
        __syncthreads();
        int woff = 0;
#pragma unroll
        for (int j = 0; j < 4; ++j) if (j < wv) woff += wtot[j];
        int excl = woff + inc - s;
        int4 r4; r4.x = excl; r4.y = excl + c0; r4.z = excl + c0 + c1; r4.w = excl + c0 + c1 + c2;
        *(int4*)(rowptr + t * 4) = r4;
        if (t == 0) rowptr[1024] = 2048;
        rp[t * 4] = r4.x; rp[t * 4 + 1] = r4.y; rp[t * 4 + 2] = r4.z; rp[t * 4 + 3] = r4.w;
        __syncthreads();
        for (int e = t; e < 2048; e += 256) {
          int d = ei[2048 + e];
          int slot = atomicAdd(&rp[d], 1);
          eord[slot] = e;
        }
      }
      return;
    }
    // ---- bx==73: root staging, B rows 960..1151 for layer by ----
    int l = blockIdx.y;
    for (int idx = t; idx < 36864; idx += 256) {
      float v = root_w[(size_t)l * 36864 + idx];
      int i = idx / 192, o = idx - i * 192;
      Btl[(size_t)l * 221184 + (i >> 3) * 9216 + (size_t)(960 + o) * 8 + (i & 7)] = (_Float16)v;
    }
    return;
  }
  // ---- worker: wave-private 4-buf gll16 pipeline over K=192 (24 tiles x 8 rows x 128 cols) ----
  int w = t >> 6, lane = t & 63;
  int l = blockIdx.y;
  int wcol = blockIdx.x * 512 + w * 128;
  const float* W2l = nn2_w + (size_t)l * 7077888;
  char* ldsbase = (char*)smem + w * 16384;
  int rlane = lane >> 5;          // sub-row 0/1 within a gll16 call
  int clane = (lane & 31) << 4;   // byte offset within 512B row chunk
  float2 nb = *(const float2*)(nn2_b + (size_t)l * 36864 + wcol + 2 * lane);

#define ISSUE(tile)                                                             \
  {                                                                             \
    _Pragma("unroll")                                                           \
    for (int j = 0; j < 4; ++j) {                                               \
      int row = (tile) * 8 + 2 * j + rlane;                                     \
      gll16((const char*)(W2l + (size_t)row * 36864 + wcol) + clane,            \
            ldsbase + ((tile) & 3) * 4096 + j * 1024 + lane * 16);              \
    }                                                                           \
  }

  ISSUE(0); ISSUE(1); ISSUE(2);
  // M[l] build (L3-absorbed redundancy, r5-proven); overlaps the prefetch latency
  if (t < 192) {
    float a0 = 0.f, a1 = 0.f, a2 = 0.f, a3 = 0.f, a4 = 0.f;
    const float* nw = nn1_w + (size_t)l * 36864 + t;
    for (int k = 0; k < 192; ++k) {
      float nv = nw[(size_t)k * 192];
      a0 += eenc_w[k] * nv;
      a1 += eenc_w[192 + k] * nv;
      a2 += eenc_w[384 + k] * nv;
      a3 += eenc_w[576 + k] * nv;
      a4 += eenc_b[k] * nv;
    }
    smem[16384 + t] = a0; smem[16576 + t] = a1; smem[16768 + t] = a2;
    smem[16960 + t] = a3; smem[17152 + t] = a4 + nn1_b[l * 192 + t];
  }
  __syncthreads();  // drains T0..T2 (they overlap M-build) + publishes M

  float2 a0 = {0.f, 0.f}, a1 = {0.f, 0.f}, a2 = {0.f, 0.f}, a3 = {0.f, 0.f}, a4 = {0.f, 0.f};
  const float* Ms = smem + 16384;
  for (int tile = 0; tile < 24; ++tile) {
    if (tile < 21) ISSUE(tile + 3);
    // in-order vmcnt: all but newest N complete => tile's 4 loads landed
    if (tile < 21)       asm volatile("s_waitcnt vmcnt(12)" ::: "memory");
    else if (tile == 21) asm volatile("s_waitcnt vmcnt(8)" ::: "memory");
    else if (tile == 22) asm volatile("s_waitcnt vmcnt(4)" ::: "memory");
    else                 asm volatile("s_waitcnt vmcnt(0)" ::: "memory");
    const float* wb = smem + w * 4096 + (tile & 3) * 1024;
    const float* Mt = Ms + tile * 8;
#pragma unroll
    for (int r = 0; r < 8; ++r) {
      float2 wv = *(const float2*)(wb + r * 128 + 2 * lane);
      float m0 = Mt[r], m1 = Mt[192 + r], m2 = Mt[384 + r], m3 = Mt[576 + r], m4 = Mt[768 + r];
      a0.x += m0 * wv.x; a0.y += m0 * wv.y;
      a1.x += m1 * wv.x; a1.y += m1 * wv.y;
      a2.x += m2 * wv.x; a2.y += m2 * wv.y;
      a3.x += m3 * wv.x; a3.y += m3 * wv.y;
      a4.x += m4 * wv.x; a4.y += m4 * wv.y;
    }
  }
#undef ISSUE
  a4.x += nb.x; a4.y += nb.y;
  int col = wcol + 2 * lane;
  {
    int i0 = col / 192, o0 = col - i0 * 192;
    _Float16* B0 = Btl + (size_t)l * 221184 + (i0 >> 3) * 9216 + (i0 & 7);
    B0[(size_t)(0 * 192 + o0) * 8] = (_Float16)a0.x;
    B0[(size_t)(1 * 192 + o0) * 8] = (_Float16)a1.x;
    B0[(size_t)(2 * 192 + o0) * 8] = (_Float16)a2.x;
    B0[(size_t)(3 * 192 + o0) * 8] = (_Float16)a3.x;
    B0[(size_t)(4 * 192 + o0) * 8] = (_Float16)a4.x;
    int c1 = col + 1;
    int i1 = c1 / 192, o1 = c1 - i1 * 192;
    _Float16* B1 = Btl + (size_t)l * 221184 + (i1 >> 3) * 9216 + (i1 & 7);
    B1[(size_t)(0 * 192 + o1) * 8] = (_Float16)a0.y;
    B1[(size_t)(1 * 192 + o1) * 8] = (_Float16)a1.y;
    B1[(size_t)(2 * 192 + o1) * 8] = (_Float16)a2.y;
    B1[(size_t)(3 * 192 + o1) * 8] = (_Float16)a3.y;
    B1[(size_t)(4 * 192 + o1) * 8] = (_Float16)a4.y;
  }
}

// ---- Y = z16 @ B (1024x1152, K=192); layer 0 builds its A-tile from Tx (cheb_out) in LDS ----
__global__ __launch_bounds__(256)
void k_y(const _Float16* __restrict__ z16, const _Float16* __restrict__ Btl,
         float* __restrict__ Y, const float* __restrict__ Tx,
         const float* __restrict__ cheb_w, const float* __restrict__ cheb_b, int layer) {
  __shared__ __align__(16) _Float16 Als[12288];  // 24 ck x 64 rows x 8 halfs (layer==0 only)
  int t = threadIdx.x;
  int w = t >> 6, lane = t & 63, l15 = lane & 15, q4 = lane >> 4;
  int e0 = blockIdx.x * 64, cb = blockIdx.y;
  if (layer == 0) {
#pragma unroll
    for (int it = 0; it < 6; ++it) {
      int u = it * 256 + t;
      int row = u & 63, ck = u >> 6;
      int n = e0 + row;
      float tv[5][4];
#pragma unroll
      for (int k = 0; k < 5; ++k) {
        float4 t4 = ((const float4*)(Tx + k * 4096))[n];
        tv[k][0] = t4.x; tv[k][1] = t4.y; tv[k][2] = t4.z; tv[k][3] = t4.w;
      }
      union { _Float16 h[8]; uint4 v; } u8;
#pragma unroll
      for (int j = 0; j < 8; ++j) {
        int o = ck * 8 + j;
        float acc = cheb_b[o];
#pragma unroll
        for (int k = 0; k < 5; ++k)
#pragma unroll
          for (int c = 0; c < 4; ++c)
            acc += tv[k][c] * cheb_w[(k * 4 + c) * 192 + o];
        u8.h[j] = (_Float16)acc;
      }
      *(uint4*)(Als + (size_t)u * 8) = u8.v;
    }
    __syncthreads();
  }
  const _Float16* Bt = Btl + (size_t)layer * 221184;
  const _Float16* ap = z16 + (((size_t)q4 * 1024) + e0 + w * 16 + l15) * 8;
  const _Float16* bp = Bt + (((size_t)q4 * 1152) + cb * 192 + l15) * 8;
  f32x4 acc[12] = {};
#pragma unroll
  for (int ks = 0; ks < 6; ++ks) {
    half8 av;
    if (layer == 0)
      av = *(const half8*)(Als + (((size_t)(ks * 4 + q4) * 64) + w * 16 + l15) * 8);
    else
      av = *(const half8*)(ap + (size_t)ks * 4 * 1024 * 8);
#pragma unroll
    for (int nt = 0; nt < 12; ++nt) {
      half8 bv = *(const half8*)(bp + (size_t)ks * 4 * 1152 * 8 + nt * 16 * 8);
      acc[nt] = __builtin_amdgcn_mfma_f32_16x16x32_f16(av, bv, acc[nt], 0, 0, 0);
    }
  }
#pragma unroll
  for (int nt = 0; nt < 12; ++nt) {
    int col = cb * 192 + nt * 16 + l15;
#pragma unroll
    for (int r = 0; r < 4; ++r) {
      int row = e0 + w * 16 + q4 * 4 + r;
      Y[(size_t)row * 1152 + col] = acc[nt][r];
    }
  }
}

// ---- gather by dst (CSR) + root + bias + residual + LN + relu (+ final for l==3) ----
__global__ __launch_bounds__(256)
void k_gn(const int* __restrict__ ei, const float* __restrict__ eattr,
          const int* __restrict__ rowptr, const int* __restrict__ eord,
          const float* __restrict__ Y, const float* __restrict__ hp,
          const float* __restrict__ cbv, const float* __restrict__ gg,
          const float* __restrict__ bb, float* __restrict__ ho,
          _Float16* __restrict__ zo, const float* __restrict__ out_w,
          const float* __restrict__ out_b, float* __restrict__ outp, int l) {
  int t = threadIdx.x, w = t >> 6, lane = t & 63;
  int n = blockIdx.x * 4 + w;
  int o0 = lane, o1 = lane + 64, o2 = lane + 128;
  float v0 = 0.f, v1 = 0.f, v2 = 0.f;
  int beg = rowptr[n], end = rowptr[n + 1];
  for (int idx = beg; idx < end; ++idx) {
    int e = eord[idx];
    int s = ei[e];
    float4 u = ((const float4*)eattr)[e];
    const float* yr = Y + (size_t)s * 1152;
    v0 += yr[o0] * u.x + yr[192 + o0] * u.y + yr[384 + o0] * u.z + yr[576 + o0] * u.w + yr[768 + o0];
    v1 += yr[o1] * u.x + yr[192 + o1] * u.y + yr[384 + o1] * u.z + yr[576 + o1] * u.w + yr[768 + o1];
    v2 += yr[o2] * u.x + yr[192 + o2] * u.y + yr[384 + o2] * u.z + yr[576 + o2] * u.w + yr[768 + o2];
  }
  const float* yn = Y + (size_t)n * 1152 + 960;
  v0 += yn[o0] + cbv[o0]; v1 += yn[o1] + cbv[o1]; v2 += yn[o2] + cbv[o2];
  if (l > 0) {
    v0 += hp[n * 192 + o0]; v1 += hp[n * 192 + o1]; v2 += hp[n * 192 + o2];
  }
  if (l < 3) {
    ho[n * 192 + o0] = v0; ho[n * 192 + o1] = v1; ho[n * 192 + o2] = v2;
  }
  float s1 = v0 + v1 + v2, s2 = v0 * v0 + v1 * v1 + v2 * v2;
#pragma unroll
  for (int off = 32; off >= 1; off >>= 1) {
    s1 += __shfl_xor(s1, off);
    s2 += __shfl_xor(s2, off);
  }
  float mu = s1 * (1.f / 192.f);
  float var = s2 * (1.f / 192.f) - mu * mu;
  float rcp = rsqrtf(var + 1e-5f);
  float z0v = fmaxf((v0 - mu) * rcp * gg[o0] + bb[o0], 0.f);
  float z1v = fmaxf((v1 - mu) * rcp * gg[o1] + bb[o1], 0.f);
  float z2v = fmaxf((v2 - mu) * rcp * gg[o2] + bb[o2], 0.f);
  if (l < 3) {
    zo[((size_t)(o0 >> 3) * 1024 + n) * 8 + (o0 & 7)] = (_Float16)z0v;
    zo[((size_t)(o1 >> 3) * 1024 + n) * 8 + (o1 & 7)] = (_Float16)z1v;
    zo[((size_t)(o2 >> 3) * 1024 + n) * 8 + (o2 & 7)] = (_Float16)z2v;
  } else {
    float a0 = z0v * out_w[o0 * 2] + z1v * out_w[o1 * 2] + z2v * out_w[o2 * 2];
    float a1 = z0v * out_w[o0 * 2 + 1] + z1v * out_w[o1 * 2 + 1] + z2v * out_w[o2 * 2 + 1];
#pragma unroll
    for (int off = 32; off >= 1; off >>= 1) {
      a0 += __shfl_xor(a0, off);
      a1 += __shfl_xor(a1, off);
    }
    if (lane == 0) {
      outp[n * 2] = a0 + out_b[0];
      outp[n * 2 + 1] = a1 + out_b[1];
    }
  }
}

// ---------------- launch ----------------
extern "C" void kernel_launch(void* const* d_in, const int* in_sizes, int n_in,
                              void* d_out, int out_size, void* d_ws, size_t ws_size,
                              hipStream_t stream) {
  const float* x      = (const float*)d_in[0];
  const int*   ei     = (const int*)  d_in[1];
  const float* eattr  = (const float*)d_in[2];
  const float* cheb_w = (const float*)d_in[4];
  const float* cheb_b = (const float*)d_in[5];
  const float* eenc_w = (const float*)d_in[6];
  const float* eenc_b = (const float*)d_in[7];
  const float* nn1_w  = (const float*)d_in[8];
  const float* nn1_b  = (const float*)d_in[9];
  const float* nn2_w  = (const float*)d_in[10];
  const float* nn2_b  = (const float*)d_in[11];
  const float* root_w = (const float*)d_in[12];
  const float* conv_b = (const float*)d_in[13];
  const float* ln_g   = (const float*)d_in[14];
  const float* ln_bb  = (const float*)d_in[15];
  const float* out_w  = (const float*)d_in[16];
  const float* out_b  = (const float*)d_in[17];
  float* outp = (float*)d_out;
  (void)in_sizes; (void)n_in; (void)out_size; (void)ws_size;

  char* p = (char*)d_ws;
  _Float16* Btl = (_Float16*)p; p += (size_t)4 * 221184 * 2;   // 1.77 MB
  float* Tx     = (float*)p;    p += 5 * 4096 * 4;
  float* Y      = (float*)p;    p += (size_t)1024 * 1152 * 4;  // 4.7 MB
  float* hA     = (float*)p;    p += 196608 * 4;
  float* hB     = (float*)p;    p += 196608 * 4;
  _Float16* zA  = (_Float16*)p; p += 196608 * 2;
  _Float16* zB  = (_Float16*)p; p += 196608 * 2;
  int* rowptr   = (int*)p;      p += 1056 * 4;
  int* eord     = (int*)p;      p += 2048 * 4;

  k_pb<<<dim3(74, 4), 256, 0, stream>>>(nn2_w, nn2_b, eenc_w, eenc_b, nn1_w, nn1_b,
                                        root_w, Btl, x, ei, Tx, rowptr, eord);

  const _Float16* zin[4] = {zA, zA, zB, zA};  // zin[0] unused (layer 0 builds A from Tx)
  _Float16* zout[4] = {zA, zB, zA, zA};       // zout[3] unused
  float* hout[4] = {hA, hB, hA, hA};          // hout[3] unused
  const float* hres[4] = {hA, hA, hB, hA};    // hres[0] unused
  for (int l = 0; l < 4; ++l) {
    k_y<<<dim3(16, 6), 256, 0, stream>>>(zin[l], Btl, Y, Tx, cheb_w, cheb_b, l);
    k_gn<<<256, 256, 0, stream>>>(ei, eattr, rowptr, eord, Y, hres[l],
                                  conv_b + (size_t)l * 192,
                                  ln_g + (size_t)((l == 3) ? 0 : (l + 1)) * 192,
                                  ln_bb + (size_t)((l == 3) ? 0 : (l + 1)) * 192,
                                  hout[l], zout[l], out_w, out_b, outp, l);
  }
}